// Round 13
// baseline (1949.999 us; speedup 1.0000x reference)
//
#include <hip/hip_runtime.h>
#include <hip/hip_bf16.h>
#include <stdint.h>

#define Bb 32
#define Tt 512
#define Dd 1024
#define Hh 1024
#define Cc 1000
#define Mm (Bb*Tt)
#define SENT 0x7F7F7F7Fu
#define PF 6

typedef float f32x4 __attribute__((ext_vector_type(4)));
typedef short bf16x8 __attribute__((ext_vector_type(8)));

#define MFMA16(a,b,c) __builtin_amdgcn_mfma_f32_16x16x32_bf16(a,b,c,0,0,0)

static __device__ __forceinline__ unsigned short f2b(float f){
  __hip_bfloat16 h = __float2bfloat16(f);
  union { __hip_bfloat16 h; unsigned short u; } cv; cv.h = h; return cv.u;
}
static __device__ __forceinline__ float b2f(unsigned short u){
  union { unsigned int i; float f; } cv; cv.i = ((unsigned int)u) << 16; return cv.f;
}

static __device__ __forceinline__ void async16(const ushort* g, ushort* l){
  __builtin_amdgcn_global_load_lds((const __attribute__((address_space(1))) unsigned int*)g,
                                   (__attribute__((address_space(3))) unsigned int*)l,
                                   16, 0, 0);
}

// h exchange:
//   FAST (same-XCD): agent scope = sc1 (bypass L1, coherent at XCD L2). R6/R8-proven.
//   safe (cross-XCD): system scope = sc0 sc1 (coherent at L3). R4-proven.
template<int FAST>
static __device__ __forceinline__ bf16x8 h_load(const ushort* p){
  bf16x8 r;
  if constexpr (FAST)
    asm volatile("global_load_dwordx4 %0, %1, off sc1" : "=v"(r) : "v"(p) : "memory");
  else
    asm volatile("global_load_dwordx4 %0, %1, off sc0 sc1" : "=v"(r) : "v"(p) : "memory");
  return r;
}
template<int FAST>
static __device__ __forceinline__ void h_store(ushort* p, unsigned int v){
  if constexpr (FAST)
    asm volatile("global_store_dword %0, %1, off sc1" :: "v"(p), "v"(v) : "memory");
  else
    asm volatile("global_store_dword %0, %1, off sc0 sc1" :: "v"(p), "v"(v) : "memory");
}

static __device__ __forceinline__ int load4sys(const int* p){
  int v;
  asm volatile("global_load_dword %0, %1, off sc0 sc1" : "=v"(v) : "v"(p) : "memory");
  asm volatile("s_waitcnt vmcnt(0)" ::: "memory");
  return v;
}
static __device__ __forceinline__ void store4sys(int* p, int v){
  asm volatile("global_store_dword %0, %1, off sc0 sc1" :: "v"(p), "v"(v) : "memory");
}

// ---------------- conversion kernels ----------------

__global__ void cvt_bf16(const float* __restrict__ in, ushort* __restrict__ out, int n4){
  int i = blockIdx.x*256 + threadIdx.x;
  if (i < n4){
    const float4 v = ((const float4*)in)[i];
    ushort4 o;
    o.x = f2b(v.x); o.y = f2b(v.y); o.z = f2b(v.z); o.w = f2b(v.w);
    ((ushort4*)out)[i] = o;
  }
}

__global__ void pad_w2(const float* __restrict__ w2, const float* __restrict__ b2,
                       ushort* __restrict__ w2p, float* __restrict__ b2p){
  int i = blockIdx.x*256 + threadIdx.x;
  int r = i >> 10, c = i & 1023;
  w2p[i] = (r < Cc) ? f2b(w2[r*1024 + c]) : (ushort)0;
  if (i < 1024) b2p[i] = (i < Cc) ? b2[i] : 0.f;
}

// ---------------- generic bf16 MFMA GEMM (m97 structure) ----------------
// PERM_A / PERM_C: buffer stored row-permuted [(m&511)*32 + (m>>9)] = [t*32+b]

template<int RELU, int OUT_BF16, int PERM_A, int PERM_C>
__global__ __launch_bounds__(256) void gemm_bt(
    const ushort* __restrict__ A, const ushort* __restrict__ Bm,
    const float* __restrict__ bias, void* __restrict__ Cp,
    int M, int N, int K, int ldc, int nout)
{
  __shared__ ushort As[128*32];
  __shared__ ushort Bs[128*32];
  const int tid  = threadIdx.x;
  const int lane = tid & 63;
  const int wave = tid >> 6;
  const int wr = wave >> 1, wc = wave & 1;
  const int r0 = lane & 15, kg = lane >> 4;
  const int m0 = blockIdx.x*128, n0 = blockIdx.y*128;

  const int lrA0 = m0 + (tid>>2);
  const int lrA1 = lrA0 + 64;
  const size_t prA0 = PERM_A ? (size_t)((lrA0 & 511)*32 + (lrA0 >> 9)) : (size_t)lrA0;
  const size_t prA1 = PERM_A ? (size_t)((lrA1 & 511)*32 + (lrA1 >> 9)) : (size_t)lrA1;
  const ushort* aG0 = A  + prA0*K + (tid&3)*8;
  const ushort* aG1 = A  + prA1*K + (tid&3)*8;
  const ushort* bG  = Bm + (size_t)(n0 + (tid>>2))*K + (tid&3)*8;
  ushort* aL = As + tid*8;
  ushort* bL = Bs + tid*8;
  const size_t rstep = (size_t)64*K;

  f32x4 acc[4][4] = {};

  for (int kt = 0; kt < K; kt += 32){
    __syncthreads();
    async16(aG0 + kt, aL);
    async16(aG1 + kt, aL + 2048);
    async16(bG + kt,         bL);
    async16(bG + kt + rstep, bL + 2048);
    __syncthreads();
    bf16x8 af[4], bf_[4];
#pragma unroll
    for (int i=0;i<4;i++) af[i]  = *(const bf16x8*)&As[(wr*64 + i*16 + r0)*32 + kg*8];
#pragma unroll
    for (int j=0;j<4;j++) bf_[j] = *(const bf16x8*)&Bs[(wc*64 + j*16 + r0)*32 + kg*8];
#pragma unroll
    for (int i=0;i<4;i++)
#pragma unroll
      for (int j=0;j<4;j++)
        acc[i][j] = MFMA16(af[i], bf_[j], acc[i][j]);
  }

  const int rowb = m0 + wr*64 + kg*4;
  const int colb = n0 + wc*64 + r0;
#pragma unroll
  for (int i=0;i<4;i++){
#pragma unroll
    for (int j=0;j<4;j++){
      const int c = colb + j*16;
      if (c >= nout) continue;
      const float bv = bias ? bias[c] : 0.f;
#pragma unroll
      for (int q=0;q<4;q++){
        const int r = rowb + i*16 + q;
        const size_t pr = PERM_C ? (size_t)((r & 511)*32 + (r >> 9)) : (size_t)r;
        float v = acc[i][j][q] + bv;
        if (RELU) v = fmaxf(v, 0.f);
        if (OUT_BF16) ((ushort*)Cp)[pr*ldc + c] = f2b(v);
        else          ((float* )Cp)[pr*ldc + c] = v;
      }
    }
  }
}

// ---------------- persistent GRU scan, batch-partitioned per XCD ----------------
// 256 WGs of 512 thr. Group g = {bid : bid%8==g} (32 members) owns batches
// [4g,4g+4); member m owns hidden units [32m,32m+32). Exchange = sentinel
// write-once rows of hsAll (the poll IS the data load — one L2 hop).
// R13: prefetch row t+PF HBM->L2 via global_load_lds into a DUMMY LDS slab —
// no VGPR destination, so no register-clobber hazard (R12's failure mode:
// un-drained asm loads land in reallocated VGPRs). Producer write-allocate
// and consumer first-poll then hit L2 instead of a ~900cy HBM miss.

#define REDN 4656   // 388 slots * 12 (97-row / 12-slot padding: <=2-way banks, 16B-aligned reads)

template<int FAST>
static __device__ __forceinline__ void scan_body(
    const int g, const int m, const int tid,
    const ushort* __restrict__ Whh, const float* __restrict__ bhh,
    const ushort* __restrict__ gxT, ushort* __restrict__ hsAll,
    float* __restrict__ red, ushort* __restrict__ dummyL)
{
  const int wave = tid >> 6;          // K-slice [wave*128, +128)
  const int lane = tid & 63;
  const int r0 = lane & 15, kg = lane >> 4;
  const int kbase = wave*128 + kg*8;

  // weight-stationary: 24 bf16x8 frags (plain loads; unified VGPR/AGPR file)
  bf16x8 wb[6][4];
#pragma unroll
  for (int n=0;n<6;n++){
    const ushort* wr_ = Whh + ((size_t)((n>>1)*1024 + m*32 + (n&1)*16 + r0))*1024 + kbase;
#pragma unroll
    for (int ks=0;ks<4;ks++)
      wb[n][ks] = *(const bf16x8*)(wr_ + ks*32);
  }

  // epilogue role: threads 0..63 (wave0), batch eb, unit pair (u0, u0+1)
  const int eb = tid >> 4;
  const int u0 = (tid & 15)*2;
  const int jg = m*32 + u0;
  float br0=0,br1=0,bz0=0,bz1=0,bn0=0,bn1=0;
  if (tid < 64){
    br0 = bhh[jg];       br1 = bhh[jg+1];
    bz0 = bhh[1024+jg];  bz1 = bhh[1024+jg+1];
    bn0 = bhh[2048+jg];  bn1 = bhh[2048+jg+1];
  }
  float hold0 = 0.f, hold1 = 0.f;

  // gx register double-buffer (wave0 only): gx(0) issued now, drained by first poll
  unsigned xr=0, xz=0, xn=0, xrN=0, xzN=0, xnN=0;
  if (tid < 64){
    const ushort* gb = gxT + (size_t)(g*4 + eb)*3072 + jg;
    asm volatile("global_load_dword %0, %1, off" : "=v"(xr) : "v"(gb));
    asm volatile("global_load_dword %0, %1, off" : "=v"(xz) : "v"(gb + 1024));
    asm volatile("global_load_dword %0, %1, off" : "=v"(xn) : "v"(gb + 2048));
  }

  for (int t = 0; t < Tt; ++t){
    const int buf = t & 1;

    // ---- poll-load h(t): this group's 4 batch rows (lanes r0>=4 duplicate r0&3).
    // The poll IS the data load: when it passes, ha[] is ready for MFMA.
    const ushort* aB = hsAll + (size_t)(t*32 + g*4 + (r0 & 3))*1024 + kbase;
    bf16x8 ha[4];
    int again;
    do {
#pragma unroll
      for (int ks=0;ks<4;ks++) ha[ks] = h_load<FAST>(aB + ks*32);
      asm volatile("s_waitcnt vmcnt(0)" ::: "memory");
      __builtin_amdgcn_sched_barrier(0);
      unsigned sent = 0;
#pragma unroll
      for (int ks=0;ks<4;ks++){
        union { bf16x8 v; unsigned u[4]; } A; A.v = ha[ks];
#pragma unroll
        for (int q=0;q<4;q++) sent |= (A.u[q] == SENT);
      }
      again = __any((int)sent);
    } while (again);

    // ---- L2 prefetch of exchange row t+PF via LDS-dest async load (hazard-
    // free: no VGPR dest; drains at next poll's vmcnt(0); dummy LDS unread).
    // Two calls at +0B and +128B touch both 128B lines of each row segment.
    if (t + PF <= Tt){
      const ushort* pB = hsAll + (size_t)((t+PF)*32 + g*4 + (r0 & 3))*1024 + kbase;
      async16(pB, dummyL);
      async16(pB + 64, dummyL);
    }

    // ---- gx(t+1) prefetch: drained by poll(t+1)'s vmcnt(0); hiding window
    // = MFMA+writes+sync+epilogue > HBM latency.
    if (tid < 64 && t+1 < Tt){
      const ushort* gb = gxT + (size_t)((t+1)*32 + g*4 + eb)*3072 + jg;
      asm volatile("global_load_dword %0, %1, off" : "=v"(xrN) : "v"(gb));
      asm volatile("global_load_dword %0, %1, off" : "=v"(xzN) : "v"(gb + 1024));
      asm volatile("global_load_dword %0, %1, off" : "=v"(xnN) : "v"(gb + 2048));
    }

    f32x4 acc[6] = {};
#pragma unroll
    for (int ks=0;ks<4;ks++)
#pragma unroll
      for (int n=0;n<6;n++)
        acc[n] = MFMA16(ha[ks], wb[n][ks], acc[n]);

    // ---- de-duplicated partial write (R11 layout: <=2-way banks, 16B reads)
    if (kg == 0){
      float* rb = red + buf*REDN;
#pragma unroll
      for (int n=0;n<6;n++)
#pragma unroll
        for (int q=0;q<4;q++)
          rb[(q*97 + n*16 + r0)*12 + wave] = acc[n][q];
    }
    __syncthreads();   // single barrier per step (red double-buffered)

    if (tid < 64){
      const float* rb = red + buf*REDN;
      float s[6];
#pragma unroll
      for (int i=0;i<6;i++){
        const int g3 = i >> 1, du = i & 1;
        const int slot = eb*97 + g3*32 + u0 + du;
        const float4 a  = *(const float4*)&rb[slot*12];
        const float4 b4 = *(const float4*)&rb[slot*12 + 4];
        s[i] = (a.x + a.y) + (a.z + a.w) + (b4.x + b4.y) + (b4.z + b4.w);
      }
      float h0, h1;
      {
        const float r = 1.f/(1.f + __expf(-(b2f((ushort)(xr & 0xffff)) + s[0] + br0)));
        const float z = 1.f/(1.f + __expf(-(b2f((ushort)(xz & 0xffff)) + s[2] + bz0)));
        const float a = b2f((ushort)(xn & 0xffff)) + r*(s[4] + bn0);
        const float e = __expf(-2.f*a);
        const float n = (1.f - e)/(1.f + e);
        h0 = (1.f - z)*n + z*hold0; hold0 = h0;
      }
      {
        const float r = 1.f/(1.f + __expf(-(b2f((ushort)(xr >> 16)) + s[1] + br1)));
        const float z = 1.f/(1.f + __expf(-(b2f((ushort)(xz >> 16)) + s[3] + bz1)));
        const float a = b2f((ushort)(xn >> 16)) + r*(s[5] + bn1);
        const float e = __expf(-2.f*a);
        const float n = (1.f - e)/(1.f + e);
        h1 = (1.f - z)*n + z*hold1; hold1 = h1;
      }
      const unsigned packed = (unsigned)f2b(h0) | ((unsigned)f2b(h1) << 16);
      // single store = data + publish (write-once, dword-atomic, sentinel-tagged)
      h_store<FAST>(hsAll + (size_t)((t+1)*32 + g*4 + eb)*1024 + jg, packed);
      xr = xrN; xz = xzN; xn = xnN;
    }
  }
}

__global__ __launch_bounds__(512, 1) void gru_scan(
    const ushort* __restrict__ Whh, const float* __restrict__ bhh,
    const ushort* __restrict__ gxT,   // [t][b][3H]
    ushort* __restrict__ hsAll,       // [Tt+1][32][1024]; rows 0..31 zeroed, rest SENT
    int* __restrict__ xccTab)         // [0..255]=XCC publish, [256..263]=decision; init -1
{
  __shared__ float red[2*REDN];
  __shared__ ushort dummyL[1024];     // prefetch sink (1KB write target, never read)
  __shared__ int fastFlag;
  const int bid = blockIdx.x;
  const int g = bid & 7, m = bid >> 3;
  const int tid = threadIdx.x;
  int* decTab = xccTab + 256;

  // mode agreement (R6-proven): publish XCC_ID; member 0 decides; bounded spin
  if (tid == 0){
    int myxcc;
    asm volatile("s_getreg_b32 %0, hwreg(HW_REG_XCC_ID)" : "=s"(myxcc));
    store4sys(&xccTab[bid], myxcc);
    if (m == 0){
      int ok = 1;
      long budget = 200000;
      for (int p = 0; p < 32 && ok; ++p){
        int v;
        do {
          v = load4sys(&xccTab[p*8 + g]);
          if (v == -1){ __builtin_amdgcn_s_sleep(1); if (--budget <= 0){ ok = 0; break; } }
        } while (v == -1);
        if (v != myxcc) ok = 0;
      }
      store4sys(&decTab[g], ok);
      fastFlag = ok;
    } else {
      int v;
      do {
        v = load4sys(&decTab[g]);
        if (v == -1) __builtin_amdgcn_s_sleep(1);
      } while (v == -1);
      fastFlag = v;
    }
  }
  __syncthreads();

  if (fastFlag) scan_body<1>(g, m, tid, Whh, bhh, gxT, hsAll, red, dummyL);
  else          scan_body<0>(g, m, tid, Whh, bhh, gxT, hsAll, red, dummyL);
}

// ---------------- launch ----------------

extern "C" void kernel_launch(void* const* d_in, const int* in_sizes, int n_in,
                              void* d_out, int out_size, void* d_ws, size_t ws_size,
                              hipStream_t stream)
{
  const float* features = (const float*)d_in[0];
  const float* Wp  = (const float*)d_in[1];
  const float* bp  = (const float*)d_in[2];
  const float* Wih = (const float*)d_in[3];
  const float* bih = (const float*)d_in[4];
  const float* Whh = (const float*)d_in[5];
  const float* bhh = (const float*)d_in[6];
  const float* W1  = (const float*)d_in[7];
  const float* b1  = (const float*)d_in[8];
  const float* W2  = (const float*)d_in[9];
  const float* b2  = (const float*)d_in[10];
  float* out = (float*)d_out;

  char* w = (char*)d_ws;
  auto alloc = [&](size_t bytes){ char* p = w; w += (bytes + 255) & ~(size_t)255; return p; };
  ushort* fb    = (ushort*)alloc((size_t)Mm*Dd*2);
  ushort* xb    = (ushort*)alloc((size_t)Mm*Hh*2);
  ushort* gxT   = (ushort*)alloc((size_t)Mm*3*Hh*2);
  ushort* hsAll = (ushort*)alloc((size_t)(Tt+1)*Bb*Hh*2);
  ushort* o1    = (ushort*)alloc((size_t)Mm*Hh*2);
  ushort* wpb   = (ushort*)alloc((size_t)Hh*Dd*2);
  ushort* wihb  = (ushort*)alloc((size_t)3*Hh*Hh*2);
  ushort* whhb  = (ushort*)alloc((size_t)3*Hh*Hh*2);
  ushort* w1b   = (ushort*)alloc((size_t)Hh*Hh*2);
  ushort* w2b   = (ushort*)alloc((size_t)1024*Hh*2);
  float*  b2p   = (float*)alloc(1024*4);
  int*    xccTab= (int*)alloc(264*4);
  ushort* hsT   = hsAll + (size_t)Bb*Hh;    // row (t*32+b) = h after step t

  // sentinel-fill h exchange buffer, zero the h(0) rows, reset handshake tables
  hipMemsetAsync(hsAll, 0x7F, (size_t)(Tt+1)*Bb*Hh*2, stream);
  hipMemsetAsync(hsAll, 0x00, (size_t)Bb*Hh*2, stream);
  hipMemsetAsync(xccTab, 0xFF, 264*4, stream);

  auto cvt = [&](const float* src, ushort* dst, size_t n){
    int n4 = (int)(n/4);
    hipLaunchKernelGGL(cvt_bf16, dim3((n4+255)/256), dim3(256), 0, stream, src, dst, n4);
  };
  cvt(features, fb, (size_t)Mm*Dd);
  cvt(Wp,  wpb,  (size_t)Hh*Dd);
  cvt(Wih, wihb, (size_t)3*Hh*Hh);
  cvt(Whh, whhb, (size_t)3*Hh*Hh);
  cvt(W1,  w1b,  (size_t)Hh*Hh);
  hipLaunchKernelGGL(pad_w2, dim3((1024*1024)/256), dim3(256), 0, stream, W2, b2, w2b, b2p);

  // x = relu(features @ Wp^T + bp)
  hipLaunchKernelGGL((gemm_bt<1,1,0,0>), dim3(Mm/128, Hh/128), dim3(256), 0, stream,
                     fb, wpb, bp, (void*)xb, Mm, Hh, Dd, Hh, Hh);
  // gxT[t][b][:] = x @ W_ih^T + b_ih   (row-permuted C write)
  hipLaunchKernelGGL((gemm_bt<0,1,0,1>), dim3(Mm/128, (3*Hh)/128), dim3(256), 0, stream,
                     xb, wihb, bih, (void*)gxT, Mm, 3*Hh, Hh, 3*Hh, 3*Hh);

  // GRU scan: 8 independent per-XCD batch groups, sentinel dataflow + L2 prefetch
  hipLaunchKernelGGL(gru_scan, dim3(256), dim3(512), 0, stream,
                     whhb, bhh, gxT, hsAll, xccTab);

  // out1 = relu(hs @ W1^T + b1)  (row-permuted A read from hsT)
  hipLaunchKernelGGL((gemm_bt<1,1,1,0>), dim3(Mm/128, Hh/128), dim3(256), 0, stream,
                     hsT, w1b, b1, (void*)o1, Mm, Hh, Hh, Hh, Hh);
  // out = out1 @ W2p^T + b2p  (store only first 1000 cols, fp32)
  hipLaunchKernelGGL((gemm_bt<0,0,0,0>), dim3(Mm/128, 1024/128), dim3(256), 0, stream,
                     o1, w2b, b2p, (void*)out, Mm, 1024, Hh, Cc, Cc);
}

// Round 14
// 1881.999 us; speedup vs baseline: 1.0361x; 1.0361x over previous
//
#include <hip/hip_runtime.h>
#include <hip/hip_bf16.h>
#include <stdint.h>

#define Bb 32
#define Tt 512
#define Dd 1024
#define Hh 1024
#define Cc 1000
#define Mm (Bb*Tt)
#define SENT 0x7F7F7F7Fu

typedef float f32x4 __attribute__((ext_vector_type(4)));
typedef short bf16x8 __attribute__((ext_vector_type(8)));

#define MFMA16(a,b,c) __builtin_amdgcn_mfma_f32_16x16x32_bf16(a,b,c,0,0,0)

static __device__ __forceinline__ unsigned short f2b(float f){
  __hip_bfloat16 h = __float2bfloat16(f);
  union { __hip_bfloat16 h; unsigned short u; } cv; cv.h = h; return cv.u;
}
static __device__ __forceinline__ float b2f(unsigned short u){
  union { unsigned int i; float f; } cv; cv.i = ((unsigned int)u) << 16; return cv.f;
}

static __device__ __forceinline__ void async16(const ushort* g, ushort* l){
  __builtin_amdgcn_global_load_lds((const __attribute__((address_space(1))) unsigned int*)g,
                                   (__attribute__((address_space(3))) unsigned int*)l,
                                   16, 0, 0);
}

// h exchange: FAST (same-XCD) = sc1 (bypass L1, coherent at XCD L2); safe = sc0 sc1 (L3).
template<int FAST>
static __device__ __forceinline__ bf16x8 h_load(const ushort* p){
  bf16x8 r;
  if constexpr (FAST)
    asm volatile("global_load_dwordx4 %0, %1, off sc1" : "=v"(r) : "v"(p) : "memory");
  else
    asm volatile("global_load_dwordx4 %0, %1, off sc0 sc1" : "=v"(r) : "v"(p) : "memory");
  return r;
}
template<int FAST>
static __device__ __forceinline__ void h_store(ushort* p, unsigned int v){
  if constexpr (FAST)
    asm volatile("global_store_dword %0, %1, off sc1" :: "v"(p), "v"(v) : "memory");
  else
    asm volatile("global_store_dword %0, %1, off sc0 sc1" :: "v"(p), "v"(v) : "memory");
}

static __device__ __forceinline__ int load4sys(const int* p){
  int v;
  asm volatile("global_load_dword %0, %1, off sc0 sc1" : "=v"(v) : "v"(p) : "memory");
  asm volatile("s_waitcnt vmcnt(0)" ::: "memory");
  return v;
}
static __device__ __forceinline__ void store4sys(int* p, int v){
  asm volatile("global_store_dword %0, %1, off sc0 sc1" :: "v"(p), "v"(v) : "memory");
}

// ---------------- conversion kernels ----------------

__global__ void cvt_bf16(const float* __restrict__ in, ushort* __restrict__ out, int n4){
  int i = blockIdx.x*256 + threadIdx.x;
  if (i < n4){
    const float4 v = ((const float4*)in)[i];
    ushort4 o;
    o.x = f2b(v.x); o.y = f2b(v.y); o.z = f2b(v.z); o.w = f2b(v.w);
    ((ushort4*)out)[i] = o;
  }
}

__global__ void pad_w2(const float* __restrict__ w2, const float* __restrict__ b2,
                       ushort* __restrict__ w2p, float* __restrict__ b2p){
  int i = blockIdx.x*256 + threadIdx.x;
  int r = i >> 10, c = i & 1023;
  w2p[i] = (r < Cc) ? f2b(w2[r*1024 + c]) : (ushort)0;
  if (i < 1024) b2p[i] = (i < Cc) ? b2[i] : 0.f;
}

// ---------------- generic bf16 MFMA GEMM (m97 structure + XCD swizzle) ----------------
// PERM_A / PERM_C: buffer stored row-permuted [(m&511)*32 + (m>>9)] = [t*32+b]

template<int RELU, int OUT_BF16, int PERM_A, int PERM_C>
__global__ __launch_bounds__(256) void gemm_bt(
    const ushort* __restrict__ A, const ushort* __restrict__ Bm,
    const float* __restrict__ bias, void* __restrict__ Cp,
    int M, int N, int K, int ldc, int nout)
{
  __shared__ ushort As[128*32];
  __shared__ ushort Bs[128*32];
  const int tid  = threadIdx.x;
  const int lane = tid & 63;
  const int wave = tid >> 6;
  const int wr = wave >> 1, wc = wave & 1;
  const int r0 = lane & 15, kg = lane >> 4;

  // bijective XCD swizzle (all launches have nwg % 8 == 0): cluster each
  // N-panel's row-blocks on one XCD so the B panel stays L2-resident (T1).
  const int nwg = gridDim.x * gridDim.y;
  const int lin = blockIdx.y * gridDim.x + blockIdx.x;
  const int cpx = nwg >> 3;
  const int swz = (lin & 7) * cpx + (lin >> 3);
  const int bx = swz % gridDim.x, by = swz / gridDim.x;

  const int m0 = bx*128, n0 = by*128;

  const int lrA0 = m0 + (tid>>2);
  const int lrA1 = lrA0 + 64;
  const size_t prA0 = PERM_A ? (size_t)((lrA0 & 511)*32 + (lrA0 >> 9)) : (size_t)lrA0;
  const size_t prA1 = PERM_A ? (size_t)((lrA1 & 511)*32 + (lrA1 >> 9)) : (size_t)lrA1;
  const ushort* aG0 = A  + prA0*K + (tid&3)*8;
  const ushort* aG1 = A  + prA1*K + (tid&3)*8;
  const ushort* bG  = Bm + (size_t)(n0 + (tid>>2))*K + (tid&3)*8;
  ushort* aL = As + tid*8;
  ushort* bL = Bs + tid*8;
  const size_t rstep = (size_t)64*K;

  f32x4 acc[4][4] = {};

  for (int kt = 0; kt < K; kt += 32){
    __syncthreads();
    async16(aG0 + kt, aL);
    async16(aG1 + kt, aL + 2048);
    async16(bG + kt,         bL);
    async16(bG + kt + rstep, bL + 2048);
    __syncthreads();
    bf16x8 af[4], bf_[4];
#pragma unroll
    for (int i=0;i<4;i++) af[i]  = *(const bf16x8*)&As[(wr*64 + i*16 + r0)*32 + kg*8];
#pragma unroll
    for (int j=0;j<4;j++) bf_[j] = *(const bf16x8*)&Bs[(wc*64 + j*16 + r0)*32 + kg*8];
#pragma unroll
    for (int i=0;i<4;i++)
#pragma unroll
      for (int j=0;j<4;j++)
        acc[i][j] = MFMA16(af[i], bf_[j], acc[i][j]);
  }

  const int rowb = m0 + wr*64 + kg*4;
  const int colb = n0 + wc*64 + r0;
#pragma unroll
  for (int i=0;i<4;i++){
#pragma unroll
    for (int j=0;j<4;j++){
      const int c = colb + j*16;
      if (c >= nout) continue;
      const float bv = bias ? bias[c] : 0.f;
#pragma unroll
      for (int q=0;q<4;q++){
        const int r = rowb + i*16 + q;
        const size_t pr = PERM_C ? (size_t)((r & 511)*32 + (r >> 9)) : (size_t)r;
        float v = acc[i][j][q] + bv;
        if (RELU) v = fmaxf(v, 0.f);
        if (OUT_BF16) ((ushort*)Cp)[pr*ldc + c] = f2b(v);
        else          ((float* )Cp)[pr*ldc + c] = v;
      }
    }
  }
}

// ---------------- persistent GRU scan + fused out1 ----------------
// 256 WGs of 512 thr. Group g = {bid : bid%8==g} (32 members) owns batches
// [4g,4g+4); member m owns hidden units [32m,32m+32). Exchange = sentinel
// write-once rows of hsAll (the poll IS the data load).
// R14: out1 = relu(hs @ W1^T + b1) fused in, pipelined: at step t, the W1
// MFMA runs on haP (= h from step t-1 = hs row t-2) INSIDE the poll's RTT
// shadow; wave1 does its epilogue parallel to wave0's gate epilogue.

#define REDN  4656   // hh reduce: 388 slots * 12
#define REDN2 1584   // out1 reduce: 132 slots * 12

template<int FAST>
static __device__ __forceinline__ void scan_body(
    const int g, const int m, const int tid,
    const ushort* __restrict__ Whh, const float* __restrict__ bhh,
    const ushort* __restrict__ W1b, const float* __restrict__ b1,
    const ushort* __restrict__ gxT, ushort* __restrict__ hsAll,
    ushort* __restrict__ o1, float* __restrict__ red, float* __restrict__ red2)
{
  const int wave = tid >> 6;          // K-slice [wave*128, +128)
  const int lane = tid & 63;
  const int r0 = lane & 15, kg = lane >> 4;
  const int kbase = wave*128 + kg*8;

  // weight-stationary: W_hh 24 frags + W1 8 frags (plain loads; unified RF)
  bf16x8 wb[6][4];
#pragma unroll
  for (int n=0;n<6;n++){
    const ushort* wr_ = Whh + ((size_t)((n>>1)*1024 + m*32 + (n&1)*16 + r0))*1024 + kbase;
#pragma unroll
    for (int ks=0;ks<4;ks++)
      wb[n][ks] = *(const bf16x8*)(wr_ + ks*32);
  }
  bf16x8 w1f[2][4];
#pragma unroll
  for (int n2=0;n2<2;n2++){
    const ushort* wr_ = W1b + ((size_t)(m*32 + n2*16 + r0))*1024 + kbase;
#pragma unroll
    for (int ks=0;ks<4;ks++)
      w1f[n2][ks] = *(const bf16x8*)(wr_ + ks*32);
  }

  // wave0 epilogue role: batch eb, unit pair (u0, u0+1)
  const int eb = tid >> 4;
  const int u0 = (tid & 15)*2;
  const int jg = m*32 + u0;
  float br0=0,br1=0,bz0=0,bz1=0,bn0=0,bn1=0;
  if (tid < 64){
    br0 = bhh[jg];       br1 = bhh[jg+1];
    bz0 = bhh[1024+jg];  bz1 = bhh[1024+jg+1];
    bn0 = bhh[2048+jg];  bn1 = bhh[2048+jg+1];
  }
  // wave1 epilogue role (out1): batch eb2, col pair (u02, u02+1)
  const int t2  = tid & 63;
  const int eb2 = t2 >> 4;
  const int u02 = (t2 & 15)*2;
  const int jg2 = m*32 + u02;
  float b1a=0, b1b=0;
  if (tid >= 64 && tid < 128){ b1a = b1[jg2]; b1b = b1[jg2+1]; }

  float hold0 = 0.f, hold1 = 0.f;

  // gx register double-buffer (wave0 only)
  unsigned xr=0, xz=0, xn=0, xrN=0, xzN=0, xnN=0;
  if (tid < 64){
    const ushort* gb = gxT + (size_t)(g*4 + eb)*3072 + jg;
    asm volatile("global_load_dword %0, %1, off" : "=v"(xr) : "v"(gb));
    asm volatile("global_load_dword %0, %1, off" : "=v"(xz) : "v"(gb + 1024));
    asm volatile("global_load_dword %0, %1, off" : "=v"(xn) : "v"(gb + 2048));
  }

  bf16x8 ha[4], haP[4];

  for (int t = 0; t <= Tt+1; ++t){
    const int buf = t & 1;
    const int polled = (t <= Tt);

    // ---- issue poll loads for row t (first attempt)
    const ushort* aB = hsAll + (size_t)(t*32 + g*4 + (r0 & 3))*1024 + kbase;
    if (polled){
#pragma unroll
      for (int ks=0;ks<4;ks++) ha[ks] = h_load<FAST>(aB + ks*32);
    }

    // ---- out1 MFMA on haP (h from step t-1 = hs row t-2), inside RTT shadow.
    // Register-only + LDS write: does not touch vmcnt.
    if (t >= 2){
      f32x4 acc2[2] = {};
#pragma unroll
      for (int ks=0;ks<4;ks++)
#pragma unroll
        for (int n2=0;n2<2;n2++)
          acc2[n2] = MFMA16(haP[ks], w1f[n2][ks], acc2[n2]);
      if (kg == 0){
        float* rb2 = red2 + buf*REDN2;
#pragma unroll
        for (int n2=0;n2<2;n2++)
#pragma unroll
          for (int q=0;q<4;q++)
            rb2[(q*33 + n2*16 + r0)*12 + wave] = acc2[n2][q];
      }
    }

    // ---- complete the poll (retry loop re-loads as before)
    if (polled){
      int again;
      for(;;){
        asm volatile("s_waitcnt vmcnt(0)" ::: "memory");
        __builtin_amdgcn_sched_barrier(0);
        unsigned sent = 0;
#pragma unroll
        for (int ks=0;ks<4;ks++){
          union { bf16x8 v; unsigned u[4]; } A; A.v = ha[ks];
#pragma unroll
          for (int q=0;q<4;q++) sent |= (A.u[q] == SENT);
        }
        again = __any((int)sent);
        if (!again) break;
#pragma unroll
        for (int ks=0;ks<4;ks++) ha[ks] = h_load<FAST>(aB + ks*32);
      }
    }

    // ---- gx(t+1) prefetch (drained by poll(t+1); off-chain)
    if (tid < 64 && t+1 < Tt){
      const ushort* gb = gxT + (size_t)((t+1)*32 + g*4 + eb)*3072 + jg;
      asm volatile("global_load_dword %0, %1, off" : "=v"(xrN) : "v"(gb));
      asm volatile("global_load_dword %0, %1, off" : "=v"(xzN) : "v"(gb + 1024));
      asm volatile("global_load_dword %0, %1, off" : "=v"(xnN) : "v"(gb + 2048));
    }

    // ---- hh MFMA + reduce write
    if (t < Tt){
      f32x4 acc[6] = {};
#pragma unroll
      for (int ks=0;ks<4;ks++)
#pragma unroll
        for (int n=0;n<6;n++)
          acc[n] = MFMA16(ha[ks], wb[n][ks], acc[n]);
      if (kg == 0){
        float* rb = red + buf*REDN;
#pragma unroll
        for (int n=0;n<6;n++)
#pragma unroll
          for (int q=0;q<4;q++)
            rb[(q*97 + n*16 + r0)*12 + wave] = acc[n][q];
      }
    }

    __syncthreads();   // single barrier per step (both reduce bufs double-buffered)

    // ---- wave0: gate epilogue + publish h(t+1)
    if (t < Tt && tid < 64){
      const float* rb = red + buf*REDN;
      float s[6];
#pragma unroll
      for (int i=0;i<6;i++){
        const int g3 = i >> 1, du = i & 1;
        const int slot = eb*97 + g3*32 + u0 + du;
        const float4 a  = *(const float4*)&rb[slot*12];
        const float4 b4 = *(const float4*)&rb[slot*12 + 4];
        s[i] = (a.x + a.y) + (a.z + a.w) + (b4.x + b4.y) + (b4.z + b4.w);
      }
      float h0, h1;
      {
        const float r = 1.f/(1.f + __expf(-(b2f((ushort)(xr & 0xffff)) + s[0] + br0)));
        const float z = 1.f/(1.f + __expf(-(b2f((ushort)(xz & 0xffff)) + s[2] + bz0)));
        const float a = b2f((ushort)(xn & 0xffff)) + r*(s[4] + bn0);
        const float e = __expf(-2.f*a);
        const float n = (1.f - e)/(1.f + e);
        h0 = (1.f - z)*n + z*hold0; hold0 = h0;
      }
      {
        const float r = 1.f/(1.f + __expf(-(b2f((ushort)(xr >> 16)) + s[1] + br1)));
        const float z = 1.f/(1.f + __expf(-(b2f((ushort)(xz >> 16)) + s[3] + bz1)));
        const float a = b2f((ushort)(xn >> 16)) + r*(s[5] + bn1);
        const float e = __expf(-2.f*a);
        const float n = (1.f - e)/(1.f + e);
        h1 = (1.f - z)*n + z*hold1; hold1 = h1;
      }
      const unsigned packed = (unsigned)f2b(h0) | ((unsigned)f2b(h1) << 16);
      h_store<FAST>(hsAll + (size_t)((t+1)*32 + g*4 + eb)*1024 + jg, packed);
      xr = xrN; xz = xzN; xn = xnN;
    }

    // ---- wave1: out1 epilogue for hs row (t-2), parallel with wave0
    if (t >= 2 && tid >= 64 && tid < 128){
      const float* rb2 = red2 + buf*REDN2;
      float s0, s1;
      {
        const int slot = eb2*33 + u02;
        const float4 a  = *(const float4*)&rb2[slot*12];
        const float4 b4 = *(const float4*)&rb2[slot*12 + 4];
        s0 = (a.x + a.y) + (a.z + a.w) + (b4.x + b4.y) + (b4.z + b4.w);
      }
      {
        const int slot = eb2*33 + u02 + 1;
        const float4 a  = *(const float4*)&rb2[slot*12];
        const float4 b4 = *(const float4*)&rb2[slot*12 + 4];
        s1 = (a.x + a.y) + (a.z + a.w) + (b4.x + b4.y) + (b4.z + b4.w);
      }
      const float o0 = fmaxf(s0 + b1a, 0.f);
      const float o1v = fmaxf(s1 + b1b, 0.f);
      const unsigned packed = (unsigned)f2b(o0) | ((unsigned)f2b(o1v) << 16);
      *(unsigned*)(o1 + (size_t)((t-2)*32 + g*4 + eb2)*1024 + jg2) = packed;
    }

    // carry ha -> haP for next iteration's out1
    if (polled){
#pragma unroll
      for (int ks=0;ks<4;ks++) haP[ks] = ha[ks];
    }
  }
}

__global__ __launch_bounds__(512, 1) void gru_scan(
    const ushort* __restrict__ Whh, const float* __restrict__ bhh,
    const ushort* __restrict__ W1b, const float* __restrict__ b1,
    const ushort* __restrict__ gxT,   // [t][b][3H]
    ushort* __restrict__ hsAll,       // [Tt+1][32][1024]; rows 0..31 zeroed, rest SENT
    ushort* __restrict__ o1,          // [t][b][1024] out1 (bf16, permuted rows)
    int* __restrict__ xccTab)         // [0..255]=XCC publish, [256..263]=decision; init -1
{
  __shared__ float red[2*REDN];
  __shared__ float red2[2*REDN2];
  __shared__ int fastFlag;
  const int bid = blockIdx.x;
  const int g = bid & 7, m = bid >> 3;
  const int tid = threadIdx.x;
  int* decTab = xccTab + 256;

  // mode agreement (R6-proven): publish XCC_ID; member 0 decides; bounded spin
  if (tid == 0){
    int myxcc;
    asm volatile("s_getreg_b32 %0, hwreg(HW_REG_XCC_ID)" : "=s"(myxcc));
    store4sys(&xccTab[bid], myxcc);
    if (m == 0){
      int ok = 1;
      long budget = 200000;
      for (int p = 0; p < 32 && ok; ++p){
        int v;
        do {
          v = load4sys(&xccTab[p*8 + g]);
          if (v == -1){ __builtin_amdgcn_s_sleep(1); if (--budget <= 0){ ok = 0; break; } }
        } while (v == -1);
        if (v != myxcc) ok = 0;
      }
      store4sys(&decTab[g], ok);
      fastFlag = ok;
    } else {
      int v;
      do {
        v = load4sys(&decTab[g]);
        if (v == -1) __builtin_amdgcn_s_sleep(1);
      } while (v == -1);
      fastFlag = v;
    }
  }
  __syncthreads();

  if (fastFlag) scan_body<1>(g, m, tid, Whh, bhh, W1b, b1, gxT, hsAll, o1, red, red2);
  else          scan_body<0>(g, m, tid, Whh, bhh, W1b, b1, gxT, hsAll, o1, red, red2);
}

// ---------------- launch ----------------

extern "C" void kernel_launch(void* const* d_in, const int* in_sizes, int n_in,
                              void* d_out, int out_size, void* d_ws, size_t ws_size,
                              hipStream_t stream)
{
  const float* features = (const float*)d_in[0];
  const float* Wp  = (const float*)d_in[1];
  const float* bp  = (const float*)d_in[2];
  const float* Wih = (const float*)d_in[3];
  const float* bih = (const float*)d_in[4];
  const float* Whh = (const float*)d_in[5];
  const float* bhh = (const float*)d_in[6];
  const float* W1  = (const float*)d_in[7];
  const float* b1  = (const float*)d_in[8];
  const float* W2  = (const float*)d_in[9];
  const float* b2  = (const float*)d_in[10];
  float* out = (float*)d_out;

  char* w = (char*)d_ws;
  auto alloc = [&](size_t bytes){ char* p = w; w += (bytes + 255) & ~(size_t)255; return p; };
  ushort* fb    = (ushort*)alloc((size_t)Mm*Dd*2);
  ushort* xb    = (ushort*)alloc((size_t)Mm*Hh*2);
  ushort* gxT   = (ushort*)alloc((size_t)Mm*3*Hh*2);
  ushort* hsAll = (ushort*)alloc((size_t)(Tt+1)*Bb*Hh*2);
  ushort* o1    = (ushort*)alloc((size_t)Mm*Hh*2);
  ushort* wpb   = (ushort*)alloc((size_t)Hh*Dd*2);
  ushort* wihb  = (ushort*)alloc((size_t)3*Hh*Hh*2);
  ushort* whhb  = (ushort*)alloc((size_t)3*Hh*Hh*2);
  ushort* w1b   = (ushort*)alloc((size_t)Hh*Hh*2);
  ushort* w2b   = (ushort*)alloc((size_t)1024*Hh*2);
  float*  b2p   = (float*)alloc(1024*4);
  int*    xccTab= (int*)alloc(264*4);

  // sentinel-fill h exchange buffer, zero the h(0) rows, reset handshake tables
  hipMemsetAsync(hsAll, 0x7F, (size_t)(Tt+1)*Bb*Hh*2, stream);
  hipMemsetAsync(hsAll, 0x00, (size_t)Bb*Hh*2, stream);
  hipMemsetAsync(xccTab, 0xFF, 264*4, stream);

  auto cvt = [&](const float* src, ushort* dst, size_t n){
    int n4 = (int)(n/4);
    hipLaunchKernelGGL(cvt_bf16, dim3((n4+255)/256), dim3(256), 0, stream, src, dst, n4);
  };
  cvt(features, fb, (size_t)Mm*Dd);
  cvt(Wp,  wpb,  (size_t)Hh*Dd);
  cvt(Wih, wihb, (size_t)3*Hh*Hh);
  cvt(Whh, whhb, (size_t)3*Hh*Hh);
  cvt(W1,  w1b,  (size_t)Hh*Hh);
  hipLaunchKernelGGL(pad_w2, dim3((1024*1024)/256), dim3(256), 0, stream, W2, b2, w2b, b2p);

  // x = relu(features @ Wp^T + bp)
  hipLaunchKernelGGL((gemm_bt<1,1,0,0>), dim3(Mm/128, Hh/128), dim3(256), 0, stream,
                     fb, wpb, bp, (void*)xb, Mm, Hh, Dd, Hh, Hh);
  // gxT[t][b][:] = x @ W_ih^T + b_ih   (row-permuted C write)
  hipLaunchKernelGGL((gemm_bt<0,1,0,1>), dim3(Mm/128, (3*Hh)/128), dim3(256), 0, stream,
                     xb, wihb, bih, (void*)gxT, Mm, 3*Hh, Hh, 3*Hh, 3*Hh);

  // GRU scan + fused out1 (relu(hs @ W1^T + b1) written to o1 in [t][b] layout)
  hipLaunchKernelGGL(gru_scan, dim3(256), dim3(512), 0, stream,
                     whhb, bhh, w1b, b1, gxT, hsAll, o1, xccTab);

  // out = out1 @ W2p^T + b2p  (A row-permuted; store only first 1000 cols, fp32)
  hipLaunchKernelGGL((gemm_bt<0,0,1,0>), dim3(Mm/128, 1024/128), dim3(256), 0, stream,
                     o1, w2b, b2p, (void*)out, Mm, 1024, Hh, Cc, Cc);
}